// Round 1
// baseline (170.374 us; speedup 1.0000x reference)
//
#include <hip/hip_runtime.h>

constexpr int B_  = 4;
constexpr int T_  = 4096;
constexpr int C_  = 1024;
constexpr int H_  = 64;
constexpr int BT_ = B_ * T_;
constexpr int NUNIT_ = 1152;   // 512-key work units per batch: sum_qt (qt/32+1)

typedef __attribute__((ext_vector_type(4))) float f32x4;
typedef __attribute__((ext_vector_type(8))) short bf16x8;
typedef __attribute__((ext_vector_type(8))) unsigned short u16x8;
typedef __attribute__((ext_vector_type(4))) unsigned short u16x4;

__device__ __forceinline__ unsigned short f32_to_bf16(float f) {
    union { float f; unsigned int u; } v;
    v.f = f;
    unsigned int r = v.u + 0x7FFFu + ((v.u >> 16) & 1u);  // RNE
    return (unsigned short)(r >> 16);
}
__device__ __forceinline__ float bf16_to_f32(unsigned short us) {
    union { unsigned int u; float f; } v;
    v.u = (unsigned int)us << 16;
    return v.f;
}
// 2^x via v_exp_f32 (hardware transcendental); __exp2f does not exist in HIP.
__device__ __forceinline__ float exp2_hw(float x) {
    return __builtin_amdgcn_exp2f(x);
}

// ---- Kernel 0: W -> fragment-order Wt (unchanged) --------------------------
__global__ __launch_bounds__(256) void wconv_kernel(
    const float* __restrict__ Wq, const float* __restrict__ Wk,
    const float* __restrict__ Wv, unsigned short* __restrict__ Wt)
{
    const int tid  = threadIdx.x;
    const int wid  = blockIdx.x * 4 + (tid >> 6);   // 0..383 = 12 ntiles x 32 ksteps
    const int lane = tid & 63;
    const int q    = lane >> 4, c = lane & 15;
    const int ntile = wid >> 5;
    const int kstep = wid & 31;
    const int n = ntile * 16 + c;                   // 0..191
    const int m = n >> 6;
    const float* W = (m == 0) ? Wq : (m == 1) ? Wk : Wv;
    const int ncol = n & 63;
    const int k0 = kstep * 32 + q * 8;
    u16x8 pk;
#pragma unroll
    for (int j = 0; j < 8; j++) pk[j] = f32_to_bf16(W[(size_t)(k0 + j) * H_ + ncol]);
    *(u16x8*)(Wt + (size_t)wid * 512 + lane * 8) = pk;
}

// ---- Kernel 1: QKV projection, fused fragment-order epilogue ---------------
// Round-13: latency-bound proj restructured for TLP.
//  - 16-row blocks of 128 threads (2 waves x 48 cols): grid 2048 -> 8
//    independent blocks/CU (vs 2), so barrier/load stalls of one block are
//    covered by the other seven.
//  - double-buffered LDS: ONE __syncthreads per 64-K step (was two).
//  - x prefetch issued AFTER the barrier, consumed at next iteration's
//    convert: nothing is in the vmem queue when __syncthreads drains
//    vmcnt(0), so the forced drain is free.
//  - blocks sharing an x-panel (half 0/1 of the 192 cols) are 1024 apart in
//    blockIdx -> same XCD (1024 % 8 == 0) -> panel hits that XCD's L2.
// Epilogue identical to round-12 (S = r0, wave covers nh..nh+47).
__global__ __launch_bounds__(128, 4) void proj_kernel(
    const float* __restrict__ x, const unsigned short* __restrict__ Wt,
    unsigned short* __restrict__ Qf, unsigned short* __restrict__ Kf,
    unsigned short* __restrict__ Vf)
{
    __shared__ __align__(16) unsigned short xs[2][16][72];
    const int t     = threadIdx.x;
    const int mtile = blockIdx.x & 1023;
    const int half_ = blockIdx.x >> 10;
    const int r0    = mtile * 16;
    const int w     = t >> 6;            // 0..1
    const int lane  = t & 63;
    const int quad  = lane >> 4;
    const int c     = lane & 15;
    const int nh    = half_ * 96 + w * 48;  // wave's 48-col n-chunk
    const int row   = t >> 3;            // 16 rows, 8 threads/row
    const int koff  = (t & 7) * 4;       // f32 column offset within 32-wide half

    f32x4 acc[3];
#pragma unroll
    for (int j = 0; j < 3; j++) acc[j] = {0.f, 0.f, 0.f, 0.f};

    const float* xp = x + (size_t)(r0 + row) * C_ + koff;
    f32x4 v0 = *(const f32x4*)xp;            // tile kk=0, cols koff..+3
    f32x4 v1 = *(const f32x4*)(xp + 32);     // tile kk=0, cols 32+koff..+3

    int p = 0;
    for (int kk = 0; kk < C_; kk += 64) {
        u16x4 pk0, pk1;
#pragma unroll
        for (int i = 0; i < 4; i++) {
            pk0[i] = f32_to_bf16(v0[i]);
            pk1[i] = f32_to_bf16(v1[i]);
        }
        *(u16x4*)&xs[p][row][koff]      = pk0;
        *(u16x4*)&xs[p][row][koff + 32] = pk1;
        __syncthreads();                       // no vmem outstanding: free drain
        if (kk + 64 < C_) {                    // prefetch next tile during compute
            v0 = *(const f32x4*)(xp + kk + 64);
            v1 = *(const f32x4*)(xp + kk + 96);
        }
#pragma unroll
        for (int ks = 0; ks < 64; ks += 32) {
            const bf16x8 a0 = *(const bf16x8*)&xs[p][c][ks + quad * 8];
            const unsigned short* bp =
                Wt + ((size_t)(nh >> 4) * 32 + ((kk + ks) >> 5)) * 512 + lane * 8;
#pragma unroll
            for (int j = 0; j < 3; j++) {
                const bf16x8 bj = *(const bf16x8*)(bp + (size_t)j * 32 * 512);
                acc[j] = __builtin_amdgcn_mfma_f32_16x16x32_bf16(a0, bj, acc[j], 0, 0, 0);
            }
        }
        p ^= 1;
    }

    // fused fragment-order epilogue (S = r0; 16-aligned)
    const int S   = r0;
    const int bS  = S >> 12;
    const int cc0 = quad * 4;
#pragma unroll
    for (int j = 0; j < 3; j++) {
        const int nt = nh + j * 16;   // wave-uniform matrix select
        if (nt < 128) {               // Q (nt<64) or K
            const int d0 = (nt < 64) ? nt : nt - 64;
            unsigned short* base = (nt < 64) ? Qf : Kf;
            const int t16  = (S & 4095) >> 4;
            const int half = d0 >> 5;
            const int q8   = ((d0 >> 4) & 1) * 2 + (c >> 3);
            const int j8   = c & 7;
            unsigned short* pq = base + ((size_t)(bS * 256 + t16)) * 1024
                               + half * 512 + q8 * 128 + j8;
#pragma unroll
            for (int r = 0; r < 4; r++) pq[(cc0 + r) * 8] = f32_to_bf16(acc[j][r]);
        } else {                      // V
            const int d0  = nt - 128;
            const int k32 = (S & 4095) >> 5;
            const int ht  = d0 >> 4;
            const int sq  = (S & 31) >> 3;   // 0 or 2
            unsigned short* pv = Vf + (((size_t)(bS * 128 + k32)) * 4 + ht) * 512 + c * 8;
#pragma unroll
            for (int r = 0; r < 4; r++) {
                const int cc = cc0 + r;
                pv[(sq + (cc >> 3)) * 128 + (cc & 7)] = f32_to_bf16(acc[j][r]);
            }
        }
    }
}

// ---- Kernel 2: causal flash attention (round-8 core; Q from Qf) ------------
// Unit = wave = (b, qt, ks): queries qt*16..+15, keys [ks*512, ks*512+512).
// qt in LOW bits (XCD balance), ks in high bits.
__global__ __launch_bounds__(256) void attn_kernel(
    const unsigned short* __restrict__ Qf, const unsigned short* __restrict__ Kf,
    const unsigned short* __restrict__ Vf, unsigned short* __restrict__ Opg,
    float* __restrict__ mlg)
{
    __shared__ __align__(16) unsigned short Pb[4][16][72];
    const int tid  = threadIdx.x;
    const int w    = tid >> 6;
    const int lane = tid & 63;
    const int quad = lane >> 4;
    const int c    = lane & 15;
    const int bid  = blockIdx.x;
    const int qt   = 255 - (bid & 255);       // qt descending within ks-group
    const int ks   = bid >> 8;
    const int g    = qt >> 5;                 // nseg-1
    if (ks > g) return;
    const int b    = w;                       // wave = batch (equal work lengths)
    const int q0   = qt * 16;
    const int k0   = ks * 512;
    const int kend = (q0 + 15 < k0 + 511) ? q0 + 15 : k0 + 511;

    // Q B-frags: coalesced 1KB wave loads from fragment-order Qf
    const unsigned short* qp = Qf + ((size_t)b * 256 + qt) * 1024 + lane * 8;
    const bf16x8 qB0 = *(const bf16x8*)qp;
    const bf16x8 qB1 = *(const bf16x8*)(qp + 512);

    f32x4 O[4];
#pragma unroll
    for (int tt = 0; tt < 4; tt++) O[tt] = {0.f, 0.f, 0.f, 0.f};
    float m = -1e30f, ls = 0.f;
    const float scale2 = 0.045084436f;        // (1/32)*log2(e): exp -> exp2

    unsigned short* P = &Pb[w][0][0];
    const int prow = c * 72;

    for (int kb = k0; kb <= kend; kb += 64) {
        const unsigned short* kfb = Kf + ((size_t)b * 256 + (kb >> 4)) * 1024 + lane * 8;
        f32x4 S[4];
#pragma unroll
        for (int tt = 0; tt < 4; tt++) {
            const bf16x8 kA0 = *(const bf16x8*)(kfb + tt * 1024);
            const bf16x8 kA1 = *(const bf16x8*)(kfb + tt * 1024 + 512);
            f32x4 s = {0.f, 0.f, 0.f, 0.f};
            s = __builtin_amdgcn_mfma_f32_16x16x32_bf16(kA0, qB0, s, 0, 0, 0);
            s = __builtin_amdgcn_mfma_f32_16x16x32_bf16(kA1, qB1, s, 0, 0, 0);
            S[tt] = s;
        }
        float sc[16];
        if (kb + 63 > q0) {                   // diagonal chunk: causal mask
#pragma unroll
            for (int tt = 0; tt < 4; tt++)
#pragma unroll
                for (int r = 0; r < 4; r++) {
                    const int key = kb + tt * 16 + quad * 4 + r;
                    sc[tt * 4 + r] = (key > q0 + c) ? -1e30f : S[tt][r] * scale2;
                }
        } else {
#pragma unroll
            for (int tt = 0; tt < 4; tt++)
#pragma unroll
                for (int r = 0; r < 4; r++) sc[tt * 4 + r] = S[tt][r] * scale2;
        }
        float mx = sc[0];
#pragma unroll
        for (int i = 1; i < 16; i++) mx = fmaxf(mx, sc[i]);
        mx = fmaxf(mx, __shfl_xor(mx, 16));
        mx = fmaxf(mx, __shfl_xor(mx, 32));
        const float mn    = fmaxf(m, mx);
        const float alpha = exp2_hw(m - mn);
        m = mn;
        float lsum = 0.f;
#pragma unroll
        for (int tt = 0; tt < 4; tt++) {
            u16x4 pk;
#pragma unroll
            for (int r = 0; r < 4; r++) {
                const float e = exp2_hw(sc[tt * 4 + r] - mn);
                lsum += e;
                pk[r] = f32_to_bf16(e);
            }
            *(u16x4*)(P + prow + tt * 16 + quad * 4) = pk;   // P[query][key]
        }
        ls = ls * alpha + lsum;                // per-lane partial (this quad's keys)
#pragma unroll
        for (int tt = 0; tt < 4; tt++)
#pragma unroll
            for (int r = 0; r < 4; r++) O[tt][r] *= alpha;

        const bf16x8 pB0 = *(const bf16x8*)(P + prow + quad * 8);
        const bf16x8 pB1 = *(const bf16x8*)(P + prow + 32 + quad * 8);

        const unsigned short* vfb = Vf + ((size_t)b * 128 + (kb >> 5)) * 2048 + lane * 8;
#pragma unroll
        for (int tt = 0; tt < 4; tt++) {
            const bf16x8 vA0 = *(const bf16x8*)(vfb + tt * 512);
            const bf16x8 vA1 = *(const bf16x8*)(vfb + 2048 + tt * 512);
            O[tt] = __builtin_amdgcn_mfma_f32_16x16x32_bf16(vA0, pB0, O[tt], 0, 0, 0);
            O[tt] = __builtin_amdgcn_mfma_f32_16x16x32_bf16(vA1, pB1, O[tt], 0, 0, 0);
        }
    }

    ls += __shfl_xor(ls, 16);                 // total l for query c
    ls += __shfl_xor(ls, 32);

    const size_t ustore = (size_t)b * NUNIT_ + qt + 16 * g * (g - 1) + g * (qt & 31) + ks;
#pragma unroll
    for (int tt = 0; tt < 4; tt++) {
        u16x4 pk;
#pragma unroll
        for (int r = 0; r < 4; r++) pk[r] = f32_to_bf16(O[tt][r]);
        *(u16x4*)(Opg + ustore * 1024 + c * 64 + tt * 16 + quad * 4) = pk;
    }
    if (lane < 16) {
        mlg[ustore * 32 + c]      = m;        // log2-domain max
        mlg[ustore * 32 + 16 + c] = ls;
    }
}

// ---- Kernel 3: merge segments + normalize (unchanged) ----------------------
__global__ __launch_bounds__(256) void merge_kernel(
    const unsigned short* __restrict__ Opg, const float* __restrict__ mlg,
    float* __restrict__ out)
{
    const int idx = blockIdx.x;               // b*256 + qt
    const int b   = idx >> 8;
    const int qt  = idx & 255;
    const int g   = qt >> 5;
    const int nseg = g + 1;
    const size_t base = (size_t)b * NUNIT_ + qt + 16 * g * (g - 1) + g * (qt & 31);
    const int t  = threadIdx.x;
    const int h  = t & 63;
    const int rg = t >> 6;
#pragma unroll
    for (int i = 0; i < 4; i++) {
        const int row = rg * 4 + i;
        float M = -1e30f;
        for (int s = 0; s < nseg; s++) M = fmaxf(M, mlg[(base + s) * 32 + row]);
        float L = 0.f, val = 0.f;
        for (int s = 0; s < nseg; s++) {
            const float e = exp2_hw(mlg[(base + s) * 32 + row] - M);
            L   = fmaf(mlg[(base + s) * 32 + 16 + row], e, L);
            val = fmaf(bf16_to_f32(Opg[(base + s) * 1024 + row * 64 + h]), e, val);
        }
        out[((size_t)b * T_ + qt * 16 + row) * H_ + h] = val / L;
    }
}

extern "C" void kernel_launch(void* const* d_in, const int* in_sizes, int n_in,
                              void* d_out, int out_size, void* d_ws, size_t ws_size,
                              hipStream_t stream) {
    const float* x  = (const float*)d_in[0];
    const float* Wq = (const float*)d_in[1];
    const float* Wk = (const float*)d_in[2];
    const float* Wv = (const float*)d_in[3];
    float* out = (float*)d_out;

    // ws: Qf|Kf|Vf (2 MiB each) | Wt 384K | Opg 9.2 MiB | mlg 576K
    unsigned short* Qf = (unsigned short*)d_ws;
    unsigned short* Kf = Qf + (size_t)BT_ * H_;
    unsigned short* Vf = Kf + (size_t)BT_ * H_;
    unsigned short* Wt = Vf + (size_t)BT_ * H_;
    unsigned short* Opg = Wt + (size_t)192 * C_;
    float*          mlg = (float*)(Opg + (size_t)B_ * NUNIT_ * 1024);

    wconv_kernel<<<96, 256, 0, stream>>>(Wq, Wk, Wv, Wt);
    proj_kernel<<<2048, 128, 0, stream>>>(x, Wt, Qf, Kf, Vf);
    attn_kernel<<<2048, 256, 0, stream>>>(Qf, Kf, Vf, Opg, mlg);
    merge_kernel<<<1024, 256, 0, stream>>>(Opg, mlg, out);
}